// Round 7
// baseline (1825.696 us; speedup 1.0000x reference)
//
#include <hip/hip_runtime.h>

typedef unsigned short u16;
typedef unsigned long long u64;
typedef __attribute__((ext_vector_type(8))) __bf16 bf16x8;
typedef __attribute__((ext_vector_type(4))) float f32x4;

#define DT_STEP 0.01f

// ---- workspace layout (bytes) ----
// Staged layout: element (row,kk) of a [rows x K] K-major matrix at
//   off_u16 = ((row>>4)*KB + (kk>>5))*512 + (((kk>>3)&3)*16 + (row&15))*8 + (kk&7)
// -> a wave's MFMA fragment load is 16B/lane at base + lane*16B.
//
// Wall : KB=16  : row k*496+i = sqrt(r_k)*L_k[i,:]          [read-only, L2]
// Aop2 : KB=176 : KB 0..127 Tflat (mutable, SYSTEM scope)
//                 KB 128..143 -0.5*G (read-only, L2)
//                 KB 144..175 -0.5*rho slots 0/1 (mutable, SYSTEM scope)
// Bop2 : KB=176 : KB 0..127 SwT (read-only, L2)
//                 KB 128..143 G (read-only, L2)
//                 KB 144..175 rho slots 0/1 (mutable, SYSTEM scope)
// bar  : grid-barrier monotonic epoch counter.
static const size_t OFF_WALL = 0;
static const size_t OFF_AOP2 = 4063232;    // 248*16*512*2
static const size_t OFF_BOP2 = 9650176;    // + 31*176*512*2
static const size_t OFF_PAD  = 15237120;   // benign-OOB pad (row-block 31)
static const size_t OFF_BAR  = 16221184;
static const size_t WS_NEED  = 16221440;

static __device__ __forceinline__ u16 f2bf(float x){
  unsigned u = __float_as_uint(x);
  u = u + 0x7FFFu + ((u >> 16) & 1u);   // RNE
  return (u16)(u >> 16);
}

static __device__ __forceinline__ size_t stx(int row, int kk, int KB){
  return ((size_t)((row >> 4) * KB + (kk >> 5)) << 9)
       + (size_t)(((((kk >> 3) & 3) * 16) + (row & 15)) << 3) + (kk & 7);
}

// System-scope (sc0 sc1) accesses: bypass the non-coherent per-XCD L2s,
// served/absorbed by the memory-side Infinity Cache -> coherent by
// construction, and no acquire-invalidate is ever needed.
static __device__ __forceinline__ bf16x8 sysld16(const u16* p){
  union { bf16x8 v; u64 u[2]; } x;
  x.u[0] = __hip_atomic_load((const u64*)p,     __ATOMIC_RELAXED, __HIP_MEMORY_SCOPE_SYSTEM);
  x.u[1] = __hip_atomic_load((const u64*)p + 1, __ATOMIC_RELAXED, __HIP_MEMORY_SCOPE_SYSTEM);
  return x.v;
}
static __device__ __forceinline__ void sysst2(u16* p, u16 v){
  __hip_atomic_store(p, v, __ATOMIC_RELAXED, __HIP_MEMORY_SCOPE_SYSTEM);
}

// Grid barrier, no acquire-invalidate: release arrive (drains vmcnt so all
// system stores reached the coherence point) + relaxed spin. Mutable-data
// reads are system-scope loads -> no L2 invalidate required.
static __device__ __forceinline__ void gbar(int* bar, int target){
  __syncthreads();
  if (threadIdx.x == 0){
    __hip_atomic_fetch_add(bar, 1, __ATOMIC_RELEASE, __HIP_MEMORY_SCOPE_AGENT);
    while (__hip_atomic_load(bar, __ATOMIC_RELAXED, __HIP_MEMORY_SCOPE_AGENT) < target)
      __builtin_amdgcn_s_sleep(2);
  }
  __syncthreads();
}

// Rotated-register-pipeline NT GEMM K-loop on staged operands.
// ASYS/BSYS select system-scope (coherent) vs normal cached loads.
template<int NKT, int DEPTH, bool ASYS, bool BSYS>
static __device__ __forceinline__ void kloop(
    f32x4 (&acc)[2][2], const u16* __restrict__ baseA,
    const u16* __restrict__ baseB, size_t strA, size_t strB)
{
  bf16x8 Ar[DEPTH][2], Br[DEPTH][2];
#define LDA(p, kt) { const u16* pa = baseA + ((size_t)(kt) << 9);              \
    if constexpr (ASYS){ Ar[p][0] = sysld16(pa); Ar[p][1] = sysld16(pa + strA); } \
    else { Ar[p][0] = *(const bf16x8*)pa; Ar[p][1] = *(const bf16x8*)(pa + strA); } }
#define LDB(p, kt) { const u16* pb = baseB + ((size_t)(kt) << 9);              \
    if constexpr (BSYS){ Br[p][0] = sysld16(pb); Br[p][1] = sysld16(pb + strB); } \
    else { Br[p][0] = *(const bf16x8*)pb; Br[p][1] = *(const bf16x8*)(pb + strB); } }
#define MF(p) \
    acc[0][0] = __builtin_amdgcn_mfma_f32_16x16x32_bf16(Ar[p][0], Br[p][0], acc[0][0], 0, 0, 0); \
    acc[0][1] = __builtin_amdgcn_mfma_f32_16x16x32_bf16(Ar[p][0], Br[p][1], acc[0][1], 0, 0, 0); \
    acc[1][0] = __builtin_amdgcn_mfma_f32_16x16x32_bf16(Ar[p][1], Br[p][0], acc[1][0], 0, 0, 0); \
    acc[1][1] = __builtin_amdgcn_mfma_f32_16x16x32_bf16(Ar[p][1], Br[p][1], acc[1][1], 0, 0, 0);
  #pragma unroll
  for (int p = 0; p < DEPTH; ++p){ LDA(p, p) LDB(p, p) }
  for (int it = 0; it < NKT - DEPTH; it += DEPTH){
    #pragma unroll
    for (int p = 0; p < DEPTH; ++p){
      MF(p)
      LDA(p, it + p + DEPTH)
      LDB(p, it + p + DEPTH)
    }
  }
  #pragma unroll
  for (int p = 0; p < DEPTH; ++p){ MF(p) }
#undef LDA
#undef LDB
#undef MF
}

// K0a: fill Wall (staged) and SwT region of Bop2 (staged). K-pads -> 0.
__global__ __launch_bounds__(256) void k0a(const float* __restrict__ L,
                                           const float* __restrict__ rates,
                                           u16* __restrict__ Wall,
                                           u16* __restrict__ Bop2){
  int id = blockIdx.x * 256 + threadIdx.x;
  if (id >= 8*496*512) return;
  int k   = id / (496*512);
  int rem = id - k*(496*512);
  int i   = rem >> 9;
  int j   = rem & 511;
  float rt = sqrtf(fabsf(rates[k]));
  float v = 0.0f;
  if (j < 496) v = rt * L[(size_t)k*246016 + i*496 + j];
  u16 h = f2bf(v);
  Wall[stx(k*496 + i, j, 16)] = h;
  Bop2[stx(i, (k << 9) + j, 176)] = h;
}

// K0b: SwC[i, k*512+j] = sqrt(r_k)*L_k[j,i] into Aop2 KB 0..127 (LDS transpose).
__global__ __launch_bounds__(256) void k0b(const float* __restrict__ L,
                                           const float* __restrict__ rates,
                                           u16* __restrict__ Aop2){
  __shared__ float tile[32][33];
  int k  = blockIdx.z;
  int i0 = blockIdx.x * 32;
  int j0 = blockIdx.y * 32;
  int tx = threadIdx.x, ty = threadIdx.y;  // 32 x 8
  float rt = sqrtf(fabsf(rates[k]));
  #pragma unroll
  for (int p = 0; p < 4; ++p){
    int j = j0 + ty + p*8;
    int i = i0 + tx;
    float v = 0.0f;
    if (j < 496 && i < 496) v = rt * L[(size_t)k*246016 + j*496 + i];
    tile[ty + p*8][tx] = v;
  }
  __syncthreads();
  #pragma unroll
  for (int p = 0; p < 4; ++p){
    int i = i0 + ty + p*8;
    int j = j0 + tx;
    if (i < 496) Aop2[stx(i, (k << 9) + j, 176)] = f2bf(tile[tx][ty + p*8]);
  }
}

// K0c: rho into slot0 (staged), zero slot1 + G pads, d_out = rho0, bar = 0.
__global__ __launch_bounds__(256) void k0c(const float* __restrict__ rho0,
                                           u16* __restrict__ Aop2,
                                           u16* __restrict__ Bop2,
                                           float* __restrict__ dout,
                                           int* __restrict__ bar){
  int id = blockIdx.x * 256 + threadIdx.x;
  if (id >= 496*512) return;
  int i = id >> 9, j = id & 511;
  float f = (j < 496) ? rho0[(size_t)i*496 + j] : 0.0f;
  Bop2[stx(i, 4608 + j, 176)] = f2bf(f);
  Aop2[stx(i, 4608 + j, 176)] = f2bf(-0.5f*f);
  Bop2[stx(i, 5120 + j, 176)] = 0;
  Aop2[stx(i, 5120 + j, 176)] = 0;
  if (j >= 496){ Bop2[stx(i, 4096 + j, 176)] = 0; Aop2[stx(i, 4096 + j, 176)] = 0; }
  if (j < 496) dout[(size_t)i*496 + j] = f;
  if (id == 0) *bar = 0;
}

// G = SwC * SwC^T, separate launch (kernel boundary flushes G into L3 so
// evolve's normal cached reads are safe). Normal loads/stores throughout.
__global__ __launch_bounds__(256, 2) void gemmG_k(
    const u16* __restrict__ Asrc, u16* Aop2, u16* Bop2){
  const int t = threadIdx.x, lane = t & 63, w = t >> 6;
  const int wm = w & 1, wn = w >> 1;
  const int tm = blockIdx.x, tn = blockIdx.y;
  const size_t laneu = (size_t)lane * 8;
  const size_t str = (size_t)176 << 9;
  const u16* baseA = Asrc + (((size_t)(tm*4 + wm*2) * 176) << 9) + laneu;
  const u16* baseB = Asrc + (((size_t)(tn*4 + wn*2) * 176) << 9) + laneu;
  f32x4 acc[2][2];
  #pragma unroll
  for (int a = 0; a < 2; ++a)
    #pragma unroll
    for (int b = 0; b < 2; ++b)
      acc[a][b] = (f32x4){0.f, 0.f, 0.f, 0.f};
  kloop<128, 4, false, false>(acc, baseA, baseB, str, str);
  const int quad = lane >> 4, c16 = lane & 15;
  #pragma unroll
  for (int mi = 0; mi < 2; ++mi)
  #pragma unroll
  for (int ni = 0; ni < 2; ++ni)
  #pragma unroll
  for (int r = 0; r < 4; ++r){
    int row = tm*64 + wm*32 + mi*16 + quad*4 + r;
    int col = tn*64 + wn*32 + ni*16 + c16;
    if (row < 496 && col < 496){
      float v = acc[mi][ni][r];
      Bop2[stx(row, 4096 + col, 176)] = f2bf(v);
      Aop2[stx(row, 4096 + col, 176)] = f2bf(-0.5f*v);
    }
  }
}

// Phase-A job: T_k = L~_k * rho. XCD-sliced decode over b in [0,512).
// A = Wall (cached), B = staged rho (SYSTEM). Epilogue -> Tflat (SYSTEM).
static __device__ __forceinline__ void jobA(
    int b, int rhoKB, const u16* __restrict__ Wall,
    u16* __restrict__ Aop2, const u16* __restrict__ Bop2)
{
  int x = b & 7, i = b >> 3;
  int tm = x*8 + (i & 7);
  int tn = i >> 3;
  if (tm >= 62) return;
  const int t = threadIdx.x, lane = t & 63, w = t >> 6;
  const int wm = w & 1, wn = w >> 1;
  const size_t laneu = (size_t)lane * 8;
  const size_t strA = (size_t)16 << 9;
  const size_t strB = (size_t)176 << 9;
  const u16* baseA = Wall + (((size_t)(tm*4 + wm*2) * 16) << 9) + laneu;
  const u16* baseB = Bop2 + (((size_t)(tn*4 + wn*2) * 176 + rhoKB) << 9) + laneu;
  f32x4 acc[2][2];
  #pragma unroll
  for (int a = 0; a < 2; ++a)
    #pragma unroll
    for (int c = 0; c < 2; ++c)
      acc[a][c] = (f32x4){0.f, 0.f, 0.f, 0.f};
  kloop<16, 4, false, true>(acc, baseA, baseB, strA, strB);
  const int quad = lane >> 4, c16 = lane & 15;
  #pragma unroll
  for (int mi = 0; mi < 2; ++mi)
  #pragma unroll
  for (int ni = 0; ni < 2; ++ni)
  #pragma unroll
  for (int r = 0; r < 4; ++r){
    int row = tm*64 + wm*32 + mi*16 + quad*4 + r;
    int col = tn*64 + wn*32 + ni*16 + c16;
    int k  = row / 496;
    int i2 = row - k*496;
    u16 hv = (col < 496) ? f2bf(acc[mi][ni][r]) : (u16)0;
    sysst2(&Aop2[stx(i2, (k << 9) + col, 176)], hv);
  }
}

// Phase-B pair decode with XCD quadrant grouping (see R5).
static __device__ __forceinline__ void pairDecode(int b, int& tm, int& tn){
  const int x = b & 7;
  const int o = b >> 3;
  if (x < 6 && o < 16){
    const int qa[6] = {0,0,0,1,1,2};
    const int qb[6] = {1,2,3,2,3,3};
    tm = qa[x]*4 + (o >> 2);
    tn = qb[x]*4 + (o & 3);
  } else {
    int n, grp;
    if (x == 6){ grp = 0; n = o; }
    else if (x == 7){ grp = 1; n = o; }
    else if (x < 3){ grp = 0; n = 17 + x; }
    else { grp = 1; n = 17 + (x - 3); }
    int qbase = (grp == 0) ? ((n < 10) ? 0 : 1) : ((n < 10) ? 2 : 3);
    int m = (n < 10) ? n : n - 10;
    int ii = 0;
    while (m >= 4 - ii){ m -= 4 - ii; ++ii; }
    tm = qbase*4 + ii;
    tn = qbase*4 + ii + m;
  }
}

// Phase-B job: rho += DT*( sum_k T_k L~_k^T - 0.5(G rho + rho G) ), symmetric.
// Per wave: 32 Tflat-kt (A SYSTEM, B cached) + 8 tail-kt (uniform type per
// wave). LDS reduce, inline finalize: dout (block-private, cached) + staged
// bf16 rho (SYSTEM) + mirror.
static __device__ __forceinline__ void jobB(
    int pairIdx, int rhoKB, int rhoKBN,
    u16* Aop2, u16* Bop2, float* dout)
{
  __shared__ float red[4][32][33];
  const int t = threadIdx.x, lane = t & 63, w = t >> 6;
  int tm, tn;
  pairDecode(pairIdx, tm, tn);               // tm <= tn
  const size_t laneu = (size_t)lane * 8;
  const size_t str = (size_t)176 << 9;
  const u16* baseA = (const u16*)Aop2 + (((size_t)(tm*2) * 176) << 9) + laneu;
  const u16* baseB = (const u16*)Bop2 + (((size_t)(tn*2) * 176) << 9) + laneu;

  f32x4 acc[2][2];
  #pragma unroll
  for (int a = 0; a < 2; ++a)
    #pragma unroll
    for (int c = 0; c < 2; ++c)
      acc[a][c] = (f32x4){0.f, 0.f, 0.f, 0.f};

  // loop 1: Tflat x SwT, kt in [w*32, w*32+32)
  kloop<32, 4, true, false>(acc, baseA + ((size_t)(w*32) << 9),
                            baseB + ((size_t)(w*32) << 9), str, str);
  // loop 2 tail: 8 kt per wave; w0/w1 -> (-0.5G)*rho, w2/w3 -> (-0.5rho)*G
  const int base = 128 + w*8;
  if (w < 2){
    kloop<8, 4, false, true>(acc, baseA + ((size_t)base << 9),
                             baseB + ((size_t)(rhoKB + base - 128) << 9), str, str);
  } else {
    kloop<8, 4, true, false>(acc, baseA + ((size_t)(rhoKB + base - 144) << 9),
                             baseB + ((size_t)(base - 16) << 9), str, str);
  }

  const int quad = lane >> 4, c16 = lane & 15;
  #pragma unroll
  for (int mi = 0; mi < 2; ++mi)
  #pragma unroll
  for (int ni = 0; ni < 2; ++ni)
  #pragma unroll
  for (int r = 0; r < 4; ++r)
    red[w][mi*16 + quad*4 + r][ni*16 + c16] = acc[mi][ni][r];
  __syncthreads();

  #pragma unroll
  for (int c = t; c < 1024; c += 256){
    int lr = c >> 5, lc = c & 31;
    float sum = red[0][lr][lc] + red[1][lr][lc] + red[2][lr][lc] + red[3][lr][lc];
    int row = tm*32 + lr, col = tn*32 + lc;
    if (row < 496 && col < 496){
      int e = row*496 + col;
      float rnew = dout[e] + DT_STEP * sum;
      u16 hb = f2bf(rnew), ha = f2bf(-0.5f*rnew);
      dout[e] = rnew;
      sysst2(&Bop2[stx(row, (rhoKBN << 5) + col, 176)], hb);
      sysst2(&Aop2[stx(row, (rhoKBN << 5) + col, 176)], ha);
      if (tm != tn){
        dout[col*496 + row] = rnew;
        sysst2(&Bop2[stx(col, (rhoKBN << 5) + row, 176)], hb);
        sysst2(&Aop2[stx(col, (rhoKBN << 5) + row, 176)], ha);
      }
    }
  }
  __syncthreads();   // red reused next call
}

// Persistent cooperative kernel: 32 x (phaseA, barrier, phaseB, barrier).
// Read-only operands stay L2-resident all 32 steps (no acquire-invalidate).
__global__ __launch_bounds__(256, 1) void evolve(
    const u16* __restrict__ Wall, u16* Aop2, u16* Bop2,
    float* dout, int* bar)
{
  const int bid = blockIdx.x;
  int ep = 0;
  for (int s = 0; s < 32; ++s){
    int rhoKB  = 144 + 16*(s & 1);
    int rhoKBN = 144 + 16*((s+1) & 1);
    jobA(bid,       rhoKB, Wall, Aop2, Bop2);
    jobA(bid + 256, rhoKB, Wall, Aop2, Bop2);
    gbar(bar, ++ep * 256);
    if (bid < 136) jobB(bid, rhoKB, rhoKBN, Aop2, Bop2, dout);
    gbar(bar, ++ep * 256);
  }
}

// ---- fallback multi-launch path (identical math) ----
__global__ __launch_bounds__(256, 2) void phaseA_k(
    const u16* __restrict__ Wall, const u16* __restrict__ Bop2src,
    int rhoKB, u16* Aop2){
  jobA(blockIdx.x, rhoKB, Wall, Aop2, Bop2src);
}
__global__ __launch_bounds__(256, 1) void phaseB_k(
    u16* Aop2, u16* Bop2, float* dout, int rhoKB, int rhoKBN){
  jobB(blockIdx.x, rhoKB, rhoKBN, Aop2, Bop2, dout);
}

extern "C" void kernel_launch(void* const* d_in, const int* in_sizes, int n_in,
                              void* d_out, int out_size, void* d_ws, size_t ws_size,
                              hipStream_t stream)
{
  (void)in_sizes; (void)n_in; (void)out_size;
  if (ws_size < WS_NEED) return;
  const float* rho0  = (const float*)d_in[0];
  // d_in[1] (H_real) provably does not affect the real forward output.
  const float* L     = (const float*)d_in[2];
  const float* rates = (const float*)d_in[3];
  float* dout = (float*)d_out;
  char* ws = (char*)d_ws;
  u16* Wall = (u16*)(ws + OFF_WALL);
  u16* Aop2 = (u16*)(ws + OFF_AOP2);
  u16* Bop2 = (u16*)(ws + OFF_BOP2);
  int* bar  = (int*)(ws + OFF_BAR);

  k0a<<<dim3((8*496*512 + 255)/256), dim3(256), 0, stream>>>(L, rates, Wall, Bop2);
  k0b<<<dim3(16,16,8), dim3(32,8), 0, stream>>>(L, rates, Aop2);
  k0c<<<dim3((496*512 + 255)/256), dim3(256), 0, stream>>>(rho0, Aop2, Bop2, dout, bar);
  // G once, separate launch (boundary flush publishes it for cached reads)
  gemmG_k<<<dim3(8,8), dim3(256), 0, stream>>>(Aop2, Aop2, Bop2);

  const u16* WallC = Wall;
  void* args[] = { (void*)&WallC, (void*)&Aop2, (void*)&Bop2, (void*)&dout, (void*)&bar };
  hipError_t err = hipLaunchCooperativeKernel((const void*)evolve, dim3(256), dim3(256),
                                              args, 0, stream);
  if (err != hipSuccess){
    for (int s = 0; s < 32; ++s){
      int rhoKB  = 144 + 16*(s & 1);
      int rhoKBN = 144 + 16*((s+1) & 1);
      phaseA_k<<<dim3(512), dim3(256), 0, stream>>>(Wall, Bop2, rhoKB, Aop2);
      phaseB_k<<<dim3(136), dim3(256), 0, stream>>>(Aop2, Bop2, dout, rhoKB, rhoKBN);
    }
  }
}

// Round 8
// 1728.512 us; speedup vs baseline: 1.0562x; 1.0562x over previous
//
#include <hip/hip_runtime.h>

typedef unsigned short u16;
typedef unsigned long long u64;
typedef __attribute__((ext_vector_type(8))) __bf16 bf16x8;
typedef __attribute__((ext_vector_type(4))) float f32x4;

#define DT_STEP 0.01f

// ---- workspace layout (bytes) ----
// Staged layout: element (row,kk) of a [rows x K] K-major matrix at
//   off_u16 = ((row>>4)*KB + (kk>>5))*512 + (((kk>>3)&3)*16 + (row&15))*8 + (kk&7)
// -> a wave's MFMA fragment load is 16B/lane at base + lane*16B, and 8
//    consecutive kk of one row are 16B contiguous (coalescible stores).
//
// Wall : KB=16  : row k*496+i = sqrt(r_k)*L_k[i,:]          [read-only, L2]
// Aop2 : KB=176 : KB 0..127 Tflat (mutable, AGENT scope)
//                 KB 128..143 -0.5*G (read-only, L2)
//                 KB 144..175 -0.5*rho slots 0/1 (mutable, AGENT scope)
// Bop2 : KB=176 : KB 0..127 SwT (read-only, L2)
//                 KB 128..143 G (read-only, L2)
//                 KB 144..175 rho slots 0/1 (mutable, AGENT scope)
// bar  : grid-barrier monotonic epoch counter.
static const size_t OFF_WALL = 0;
static const size_t OFF_AOP2 = 4063232;    // 248*16*512*2
static const size_t OFF_BOP2 = 9650176;    // + 31*176*512*2
static const size_t OFF_PAD  = 15237120;   // benign-OOB pad (row-block 31)
static const size_t OFF_BAR  = 16221184;
static const size_t WS_NEED  = 16221440;

static __device__ __forceinline__ u16 f2bf(float x){
  unsigned u = __float_as_uint(x);
  u = u + 0x7FFFu + ((u >> 16) & 1u);   // RNE
  return (u16)(u >> 16);
}

static __device__ __forceinline__ size_t stx(int row, int kk, int KB){
  return ((size_t)((row >> 4) * KB + (kk >> 5)) << 9)
       + (size_t)(((((kk >> 3) & 3) * 16) + (row & 15)) << 3) + (kk & 7);
}

// AGENT-scope (device-coherent) accesses: bypass the non-coherent per-XCD
// L2s, served at the memory-side coherence point (Infinity Cache) -> no
// acquire-invalidate needed anywhere, and much cheaper than SYSTEM scope.
static __device__ __forceinline__ bf16x8 agld16(const u16* p){
  union { bf16x8 v; u64 u[2]; } x;
  x.u[0] = __hip_atomic_load((const u64*)p,     __ATOMIC_RELAXED, __HIP_MEMORY_SCOPE_AGENT);
  x.u[1] = __hip_atomic_load((const u64*)p + 1, __ATOMIC_RELAXED, __HIP_MEMORY_SCOPE_AGENT);
  return x.v;
}
static __device__ __forceinline__ void agst16(u16* p, u64 lo, u64 hi){
  __hip_atomic_store((u64*)p,     lo, __ATOMIC_RELAXED, __HIP_MEMORY_SCOPE_AGENT);
  __hip_atomic_store((u64*)p + 1, hi, __ATOMIC_RELAXED, __HIP_MEMORY_SCOPE_AGENT);
}

// Grid barrier: release arrive (drains outstanding agent stores) + relaxed
// spin. No acquire-invalidate: all cross-block mutable reads are agent-scope.
static __device__ __forceinline__ void gbar(int* bar, int target){
  __syncthreads();
  if (threadIdx.x == 0){
    __hip_atomic_fetch_add(bar, 1, __ATOMIC_RELEASE, __HIP_MEMORY_SCOPE_AGENT);
    while (__hip_atomic_load(bar, __ATOMIC_RELAXED, __HIP_MEMORY_SCOPE_AGENT) < target)
      __builtin_amdgcn_s_sleep(2);
  }
  __syncthreads();
}

// Rotated-register-pipeline NT GEMM K-loop on staged operands.
// ASYS/BSYS select agent-scope (coherent) vs normal cached loads.
template<int NKT, int DEPTH, bool ASYS, bool BSYS>
static __device__ __forceinline__ void kloop(
    f32x4 (&acc)[2][2], const u16* __restrict__ baseA,
    const u16* __restrict__ baseB, size_t strA, size_t strB)
{
  bf16x8 Ar[DEPTH][2], Br[DEPTH][2];
#define LDA(p, kt) { const u16* pa = baseA + ((size_t)(kt) << 9);              \
    if constexpr (ASYS){ Ar[p][0] = agld16(pa); Ar[p][1] = agld16(pa + strA); } \
    else { Ar[p][0] = *(const bf16x8*)pa; Ar[p][1] = *(const bf16x8*)(pa + strA); } }
#define LDB(p, kt) { const u16* pb = baseB + ((size_t)(kt) << 9);              \
    if constexpr (BSYS){ Br[p][0] = agld16(pb); Br[p][1] = agld16(pb + strB); } \
    else { Br[p][0] = *(const bf16x8*)pb; Br[p][1] = *(const bf16x8*)(pb + strB); } }
#define MF(p) \
    acc[0][0] = __builtin_amdgcn_mfma_f32_16x16x32_bf16(Ar[p][0], Br[p][0], acc[0][0], 0, 0, 0); \
    acc[0][1] = __builtin_amdgcn_mfma_f32_16x16x32_bf16(Ar[p][0], Br[p][1], acc[0][1], 0, 0, 0); \
    acc[1][0] = __builtin_amdgcn_mfma_f32_16x16x32_bf16(Ar[p][1], Br[p][0], acc[1][0], 0, 0, 0); \
    acc[1][1] = __builtin_amdgcn_mfma_f32_16x16x32_bf16(Ar[p][1], Br[p][1], acc[1][1], 0, 0, 0);
  #pragma unroll
  for (int p = 0; p < DEPTH; ++p){ LDA(p, p) LDB(p, p) }
  for (int it = 0; it < NKT - DEPTH; it += DEPTH){
    #pragma unroll
    for (int p = 0; p < DEPTH; ++p){
      MF(p)
      LDA(p, it + p + DEPTH)
      LDB(p, it + p + DEPTH)
    }
  }
  #pragma unroll
  for (int p = 0; p < DEPTH; ++p){ MF(p) }
#undef LDA
#undef LDB
#undef MF
}

// K0a: fill Wall (staged) and SwT region of Bop2 (staged). K-pads -> 0.
__global__ __launch_bounds__(256) void k0a(const float* __restrict__ L,
                                           const float* __restrict__ rates,
                                           u16* __restrict__ Wall,
                                           u16* __restrict__ Bop2){
  int id = blockIdx.x * 256 + threadIdx.x;
  if (id >= 8*496*512) return;
  int k   = id / (496*512);
  int rem = id - k*(496*512);
  int i   = rem >> 9;
  int j   = rem & 511;
  float rt = sqrtf(fabsf(rates[k]));
  float v = 0.0f;
  if (j < 496) v = rt * L[(size_t)k*246016 + i*496 + j];
  u16 h = f2bf(v);
  Wall[stx(k*496 + i, j, 16)] = h;
  Bop2[stx(i, (k << 9) + j, 176)] = h;
}

// K0b: SwC[i, k*512+j] = sqrt(r_k)*L_k[j,i] into Aop2 KB 0..127 (LDS transpose).
__global__ __launch_bounds__(256) void k0b(const float* __restrict__ L,
                                           const float* __restrict__ rates,
                                           u16* __restrict__ Aop2){
  __shared__ float tile[32][33];
  int k  = blockIdx.z;
  int i0 = blockIdx.x * 32;
  int j0 = blockIdx.y * 32;
  int tx = threadIdx.x, ty = threadIdx.y;  // 32 x 8
  float rt = sqrtf(fabsf(rates[k]));
  #pragma unroll
  for (int p = 0; p < 4; ++p){
    int j = j0 + ty + p*8;
    int i = i0 + tx;
    float v = 0.0f;
    if (j < 496 && i < 496) v = rt * L[(size_t)k*246016 + j*496 + i];
    tile[ty + p*8][tx] = v;
  }
  __syncthreads();
  #pragma unroll
  for (int p = 0; p < 4; ++p){
    int i = i0 + ty + p*8;
    int j = j0 + tx;
    if (i < 496) Aop2[stx(i, (k << 9) + j, 176)] = f2bf(tile[tx][ty + p*8]);
  }
}

// K0c: rho into slot0 (staged), zero slot1 + G pads, d_out = rho0, bar = 0.
__global__ __launch_bounds__(256) void k0c(const float* __restrict__ rho0,
                                           u16* __restrict__ Aop2,
                                           u16* __restrict__ Bop2,
                                           float* __restrict__ dout,
                                           int* __restrict__ bar){
  int id = blockIdx.x * 256 + threadIdx.x;
  if (id >= 496*512) return;
  int i = id >> 9, j = id & 511;
  float f = (j < 496) ? rho0[(size_t)i*496 + j] : 0.0f;
  Bop2[stx(i, 4608 + j, 176)] = f2bf(f);
  Aop2[stx(i, 4608 + j, 176)] = f2bf(-0.5f*f);
  Bop2[stx(i, 5120 + j, 176)] = 0;
  Aop2[stx(i, 5120 + j, 176)] = 0;
  if (j >= 496){ Bop2[stx(i, 4096 + j, 176)] = 0; Aop2[stx(i, 4096 + j, 176)] = 0; }
  if (j < 496) dout[(size_t)i*496 + j] = f;
  if (id == 0) *bar = 0;
}

// G = SwC * SwC^T, separate launch (kernel boundary publishes G for cached
// reads). Normal loads/stores throughout.
__global__ __launch_bounds__(256, 2) void gemmG_k(
    const u16* __restrict__ Asrc, u16* Aop2, u16* Bop2){
  const int t = threadIdx.x, lane = t & 63, w = t >> 6;
  const int wm = w & 1, wn = w >> 1;
  const int tm = blockIdx.x, tn = blockIdx.y;
  const size_t laneu = (size_t)lane * 8;
  const size_t str = (size_t)176 << 9;
  const u16* baseA = Asrc + (((size_t)(tm*4 + wm*2) * 176) << 9) + laneu;
  const u16* baseB = Asrc + (((size_t)(tn*4 + wn*2) * 176) << 9) + laneu;
  f32x4 acc[2][2];
  #pragma unroll
  for (int a = 0; a < 2; ++a)
    #pragma unroll
    for (int b = 0; b < 2; ++b)
      acc[a][b] = (f32x4){0.f, 0.f, 0.f, 0.f};
  kloop<128, 4, false, false>(acc, baseA, baseB, str, str);
  const int quad = lane >> 4, c16 = lane & 15;
  #pragma unroll
  for (int mi = 0; mi < 2; ++mi)
  #pragma unroll
  for (int ni = 0; ni < 2; ++ni)
  #pragma unroll
  for (int r = 0; r < 4; ++r){
    int row = tm*64 + wm*32 + mi*16 + quad*4 + r;
    int col = tn*64 + wn*32 + ni*16 + c16;
    if (row < 496 && col < 496){
      float v = acc[mi][ni][r];
      Bop2[stx(row, 4096 + col, 176)] = f2bf(v);
      Aop2[stx(row, 4096 + col, 176)] = f2bf(-0.5f*v);
    }
  }
}

// Phase-A job: T_k = L~_k * rho. XCD-sliced decode over b in [0,512).
// A = Wall (cached, L2-resident per XCD), B = staged rho (AGENT).
// Epilogue: LDS transpose of the 64x64 C tile -> coalesced 16B AGENT stores.
static __device__ __forceinline__ void jobA(
    int b, int rhoKB, const u16* __restrict__ Wall,
    u16* __restrict__ Aop2, const u16* __restrict__ Bop2, float* lds)
{
  int x = b & 7, i = b >> 3;
  int tm = x*8 + (i & 7);
  int tn = i >> 3;
  if (tm >= 62) return;                      // block-uniform
  const int t = threadIdx.x, lane = t & 63, w = t >> 6;
  const int wm = w & 1, wn = w >> 1;
  const size_t laneu = (size_t)lane * 8;
  const size_t strA = (size_t)16 << 9;
  const size_t strB = (size_t)176 << 9;
  const u16* baseA = Wall + (((size_t)(tm*4 + wm*2) * 16) << 9) + laneu;
  const u16* baseB = Bop2 + (((size_t)(tn*4 + wn*2) * 176 + rhoKB) << 9) + laneu;
  f32x4 acc[2][2];
  #pragma unroll
  for (int a = 0; a < 2; ++a)
    #pragma unroll
    for (int c = 0; c < 2; ++c)
      acc[a][c] = (f32x4){0.f, 0.f, 0.f, 0.f};
  kloop<16, 4, false, true>(acc, baseA, baseB, strA, strB);

  float (*T)[66] = (float(*)[66])lds;        // 64 x 66 view of the 4224-f32 buffer
  const int quad = lane >> 4, c16 = lane & 15;
  #pragma unroll
  for (int mi = 0; mi < 2; ++mi)
  #pragma unroll
  for (int ni = 0; ni < 2; ++ni)
  #pragma unroll
  for (int r = 0; r < 4; ++r)
    T[wm*32 + mi*16 + quad*4 + r][wn*32 + ni*16 + c16] = acc[mi][ni][r];
  __syncthreads();
  #pragma unroll
  for (int rep = 0; rep < 2; ++rep){
    int tt = t + rep*256;
    int lr = tt >> 3, oct = tt & 7;
    int row = tm*64 + lr;
    int colb = tn*64 + oct*8;
    int k = row / 496, i2 = row - k*496;
    union { u16 h[8]; u64 q[2]; } P;
    #pragma unroll
    for (int j = 0; j < 8; ++j)
      P.h[j] = (colb + j < 496) ? f2bf(T[lr][oct*8 + j]) : (u16)0;
    agst16(&Aop2[stx(i2, (k << 9) + colb, 176)], P.q[0], P.q[1]);
  }
  __syncthreads();
}

// Phase-B pair decode with XCD quadrant grouping (see R5).
static __device__ __forceinline__ void pairDecode(int b, int& tm, int& tn){
  const int x = b & 7;
  const int o = b >> 3;
  if (x < 6 && o < 16){
    const int qa[6] = {0,0,0,1,1,2};
    const int qb[6] = {1,2,3,2,3,3};
    tm = qa[x]*4 + (o >> 2);
    tn = qb[x]*4 + (o & 3);
  } else {
    int n, grp;
    if (x == 6){ grp = 0; n = o; }
    else if (x == 7){ grp = 1; n = o; }
    else if (x < 3){ grp = 0; n = 17 + x; }
    else { grp = 1; n = 17 + (x - 3); }
    int qbase = (grp == 0) ? ((n < 10) ? 0 : 1) : ((n < 10) ? 2 : 3);
    int m = (n < 10) ? n : n - 10;
    int ii = 0;
    while (m >= 4 - ii){ m -= 4 - ii; ++ii; }
    tm = qbase*4 + ii;
    tn = qbase*4 + ii + m;
  }
}

// Phase-B job: rho += DT*( sum_k T_k L~_k^T - 0.5(G rho + rho G) ), symmetric.
// Tflat/rho reads AGENT, SwT/G reads cached. Two-pass epilogue:
// pass1 reduce + rho update (cached dout, block-private) into LDS;
// pass2 coalesced 16B AGENT staged stores (+ mirror via LDS transpose).
static __device__ __forceinline__ void jobB(
    int pairIdx, int rhoKB, int rhoKBN,
    u16* Aop2, u16* Bop2, float* dout, float* lds)
{
  float (*red)[32][33] = (float(*)[32][33])lds;
  const int t = threadIdx.x, lane = t & 63, w = t >> 6;
  int tm, tn;
  pairDecode(pairIdx, tm, tn);               // tm <= tn
  const size_t laneu = (size_t)lane * 8;
  const size_t str = (size_t)176 << 9;
  const u16* baseA = (const u16*)Aop2 + (((size_t)(tm*2) * 176) << 9) + laneu;
  const u16* baseB = (const u16*)Bop2 + (((size_t)(tn*2) * 176) << 9) + laneu;

  f32x4 acc[2][2];
  #pragma unroll
  for (int a = 0; a < 2; ++a)
    #pragma unroll
    for (int c = 0; c < 2; ++c)
      acc[a][c] = (f32x4){0.f, 0.f, 0.f, 0.f};

  // loop 1: Tflat x SwT, kt in [w*32, w*32+32)
  kloop<32, 4, true, false>(acc, baseA + ((size_t)(w*32) << 9),
                            baseB + ((size_t)(w*32) << 9), str, str);
  // loop 2 tail: 8 kt/wave; w0/w1 -> (-0.5G)*rho, w2/w3 -> (-0.5rho)*G
  const int base = 128 + w*8;
  if (w < 2){
    kloop<8, 4, false, true>(acc, baseA + ((size_t)base << 9),
                             baseB + ((size_t)(rhoKB + base - 128) << 9), str, str);
  } else {
    kloop<8, 4, true, false>(acc, baseA + ((size_t)(rhoKB + base - 144) << 9),
                             baseB + ((size_t)(base - 16) << 9), str, str);
  }

  const int quad = lane >> 4, c16 = lane & 15;
  #pragma unroll
  for (int mi = 0; mi < 2; ++mi)
  #pragma unroll
  for (int ni = 0; ni < 2; ++ni)
  #pragma unroll
  for (int r = 0; r < 4; ++r)
    red[w][mi*16 + quad*4 + r][ni*16 + c16] = acc[mi][ni][r];
  __syncthreads();

  // pass 1: reduce 4 waves, rho update (cached, block-private), rnew -> LDS
  #pragma unroll
  for (int c = t; c < 1024; c += 256){
    int lr = c >> 5, lc = c & 31;
    float sum = red[0][lr][lc] + red[1][lr][lc] + red[2][lr][lc] + red[3][lr][lc];
    int row = tm*32 + lr, col = tn*32 + lc;
    float rnew = 0.0f;
    if (row < 496 && col < 496){
      int e = row*496 + col;
      rnew = dout[e] + DT_STEP * sum;
      dout[e] = rnew;
      if (tm != tn) dout[col*496 + row] = rnew;
    }
    red[0][lr][lc] = rnew;
  }
  __syncthreads();

  // pass 2: staged bf16 rho, 16B coalesced agent stores
  {
    int tt = t & 127;
    int lr = tt >> 2, oct = tt & 3;
    if (t < 128){
      int row = tm*32 + lr, colb = tn*32 + oct*8;
      if (row < 496 && colb < 496){
        union { u16 h[8]; u64 q[2]; } B_, A_;
        #pragma unroll
        for (int j = 0; j < 8; ++j){
          float v = red[0][lr][oct*8 + j];
          B_.h[j] = f2bf(v); A_.h[j] = f2bf(-0.5f*v);
        }
        agst16(&Bop2[stx(row, (rhoKBN << 5) + colb, 176)], B_.q[0], B_.q[1]);
        agst16(&Aop2[stx(row, (rhoKBN << 5) + colb, 176)], A_.q[0], A_.q[1]);
      }
    } else if (tm != tn){
      int row = tn*32 + lr, colb = tm*32 + oct*8;   // mirror tile
      if (row < 496){
        union { u16 h[8]; u64 q[2]; } B_, A_;
        #pragma unroll
        for (int j = 0; j < 8; ++j){
          float v = red[0][oct*8 + j][lr];          // transposed read
          B_.h[j] = f2bf(v); A_.h[j] = f2bf(-0.5f*v);
        }
        agst16(&Bop2[stx(row, (rhoKBN << 5) + colb, 176)], B_.q[0], B_.q[1]);
        agst16(&Aop2[stx(row, (rhoKBN << 5) + colb, 176)], A_.q[0], A_.q[1]);
      }
    }
  }
  __syncthreads();
}

// Persistent cooperative kernel: 32 x (phaseA, barrier, phaseB, barrier).
// Read-only operands stay L2-resident; mutable traffic is agent-scope.
__global__ __launch_bounds__(256, 1) void evolve(
    const u16* __restrict__ Wall, u16* Aop2, u16* Bop2,
    float* dout, int* bar)
{
  __shared__ float lds[4224];
  const int bid = blockIdx.x;
  int ep = 0;
  for (int s = 0; s < 32; ++s){
    int rhoKB  = 144 + 16*(s & 1);
    int rhoKBN = 144 + 16*((s+1) & 1);
    jobA(bid,       rhoKB, Wall, Aop2, Bop2, lds);
    jobA(bid + 256, rhoKB, Wall, Aop2, Bop2, lds);
    gbar(bar, ++ep * 256);
    if (bid < 136) jobB(bid, rhoKB, rhoKBN, Aop2, Bop2, dout, lds);
    gbar(bar, ++ep * 256);
  }
}

// ---- fallback multi-launch path (identical math) ----
__global__ __launch_bounds__(256, 2) void phaseA_k(
    const u16* __restrict__ Wall, const u16* __restrict__ Bop2src,
    int rhoKB, u16* Aop2){
  __shared__ float lds[4224];
  jobA(blockIdx.x, rhoKB, Wall, Aop2, Bop2src, lds);
}
__global__ __launch_bounds__(256, 1) void phaseB_k(
    u16* Aop2, u16* Bop2, float* dout, int rhoKB, int rhoKBN){
  __shared__ float lds[4224];
  jobB(blockIdx.x, rhoKB, rhoKBN, Aop2, Bop2, dout, lds);
}

extern "C" void kernel_launch(void* const* d_in, const int* in_sizes, int n_in,
                              void* d_out, int out_size, void* d_ws, size_t ws_size,
                              hipStream_t stream)
{
  (void)in_sizes; (void)n_in; (void)out_size;
  if (ws_size < WS_NEED) return;
  const float* rho0  = (const float*)d_in[0];
  // d_in[1] (H_real) provably does not affect the real forward output.
  const float* L     = (const float*)d_in[2];
  const float* rates = (const float*)d_in[3];
  float* dout = (float*)d_out;
  char* ws = (char*)d_ws;
  u16* Wall = (u16*)(ws + OFF_WALL);
  u16* Aop2 = (u16*)(ws + OFF_AOP2);
  u16* Bop2 = (u16*)(ws + OFF_BOP2);
  int* bar  = (int*)(ws + OFF_BAR);

  k0a<<<dim3((8*496*512 + 255)/256), dim3(256), 0, stream>>>(L, rates, Wall, Bop2);
  k0b<<<dim3(16,16,8), dim3(32,8), 0, stream>>>(L, rates, Aop2);
  k0c<<<dim3((496*512 + 255)/256), dim3(256), 0, stream>>>(rho0, Aop2, Bop2, dout, bar);
  // G once, separate launch (boundary flush publishes it for cached reads)
  gemmG_k<<<dim3(8,8), dim3(256), 0, stream>>>(Aop2, Aop2, Bop2);

  const u16* WallC = Wall;
  void* args[] = { (void*)&WallC, (void*)&Aop2, (void*)&Bop2, (void*)&dout, (void*)&bar };
  hipError_t err = hipLaunchCooperativeKernel((const void*)evolve, dim3(256), dim3(256),
                                              args, 0, stream);
  if (err != hipSuccess){
    for (int s = 0; s < 32; ++s){
      int rhoKB  = 144 + 16*(s & 1);
      int rhoKBN = 144 + 16*((s+1) & 1);
      phaseA_k<<<dim3(512), dim3(256), 0, stream>>>(Wall, Bop2, rhoKB, Aop2);
      phaseB_k<<<dim3(136), dim3(256), 0, stream>>>(Aop2, Bop2, dout, rhoKB, rhoKBN);
    }
  }
}

// Round 9
// 774.622 us; speedup vs baseline: 2.3569x; 2.2314x over previous
//
#include <hip/hip_runtime.h>

typedef unsigned short u16;
typedef unsigned long long u64;
typedef __attribute__((ext_vector_type(8))) __bf16 bf16x8;
typedef __attribute__((ext_vector_type(4))) float f32x4;

#define DT_STEP 0.01f

// ---- workspace layout (bytes) ----
// Staged layout: element (row,kk) of a [rows x K] K-major matrix at
//   off_u16 = ((row>>4)*KB + (kk>>5))*512 + (((kk>>3)&3)*16 + (row&15))*8 + (kk&7)
// -> a wave's MFMA fragment load is 16B/lane at base + lane*16B; 8
//    consecutive kk of one row are 16B contiguous (coalesced stores).
//
// Wall : 4480 rows x 512 K (KB=16, 280 row-blocks)
//        rows k*496+i, k=0..7 : sqrt(r_k)*L_k[i,:]   (k0a)
//        rows 3968+i          : G[i,:]               (gemmG)
//        rows 4464..4479      : zero pad             (k0c)
// Aop2 : 496 rows x 5632 K (KB=176) : KB 0..127 Tflat (T_k = L~_k rho)
//                                     KB 128..143 T9 (G rho)
//                                     KB 144..175 unused
// Bop2 : 496 rows x 5632 K (KB=176) : KB 0..127 SwT (sqrt(r_k)*L_k)
//                                     KB 128..143 unused (legacy G)
//                                     KB 144..175 rho slots 0/1
// Benign OOB reads (row-block 31 of Aop2/Bop2, rows 496..511, results
// guarded away) stay inside WS_NEED.
static const size_t OFF_WALL = 0;
static const size_t OFF_AOP2 = 4587520;    // 280*16*512*2
static const size_t OFF_BOP2 = 10174464;   // + 31*176*512*2
static const size_t WS_NEED  = 16221440;   // proven available since R0

static __device__ __forceinline__ u16 f2bf(float x){
  unsigned u = __float_as_uint(x);
  u = u + 0x7FFFu + ((u >> 16) & 1u);   // RNE
  return (u16)(u >> 16);
}
static __device__ __forceinline__ float bf2f(u16 h){
  return __uint_as_float(((unsigned)h) << 16);
}

static __device__ __forceinline__ size_t stx(int row, int kk, int KB){
  return ((size_t)((row >> 4) * KB + (kk >> 5)) << 9)
       + (size_t)(((((kk >> 3) & 3) * 16) + (row & 15)) << 3) + (kk & 7);
}

// Rotated-register-pipeline NT GEMM K-loop on staged operands (all cached).
// Requires (NKT-DEPTH) % DEPTH == 0.
template<int NKT, int DEPTH>
static __device__ __forceinline__ void kloop(
    f32x4 (&acc)[2][2], const u16* __restrict__ baseA,
    const u16* __restrict__ baseB, size_t strA, size_t strB)
{
  bf16x8 Ar[DEPTH][2], Br[DEPTH][2];
#define LDAB(p, kt) { const u16* pa = baseA + ((size_t)(kt) << 9);             \
    const u16* pb = baseB + ((size_t)(kt) << 9);                               \
    Ar[p][0] = *(const bf16x8*)pa; Ar[p][1] = *(const bf16x8*)(pa + strA);     \
    Br[p][0] = *(const bf16x8*)pb; Br[p][1] = *(const bf16x8*)(pb + strB); }
#define MF(p) \
    acc[0][0] = __builtin_amdgcn_mfma_f32_16x16x32_bf16(Ar[p][0], Br[p][0], acc[0][0], 0, 0, 0); \
    acc[0][1] = __builtin_amdgcn_mfma_f32_16x16x32_bf16(Ar[p][0], Br[p][1], acc[0][1], 0, 0, 0); \
    acc[1][0] = __builtin_amdgcn_mfma_f32_16x16x32_bf16(Ar[p][1], Br[p][0], acc[1][0], 0, 0, 0); \
    acc[1][1] = __builtin_amdgcn_mfma_f32_16x16x32_bf16(Ar[p][1], Br[p][1], acc[1][1], 0, 0, 0);
  #pragma unroll
  for (int p = 0; p < DEPTH; ++p){ LDAB(p, p) }
  for (int it = 0; it < NKT - DEPTH; it += DEPTH){
    #pragma unroll
    for (int p = 0; p < DEPTH; ++p){
      MF(p)
      LDAB(p, it + p + DEPTH)
    }
  }
  #pragma unroll
  for (int p = 0; p < DEPTH; ++p){ MF(p) }
#undef LDAB
#undef MF
}

// K0a: fill Wall k=0..7 (staged) and SwT region of Bop2. K-pads -> 0.
__global__ __launch_bounds__(256) void k0a(const float* __restrict__ L,
                                           const float* __restrict__ rates,
                                           u16* __restrict__ Wall,
                                           u16* __restrict__ Bop2){
  int id = blockIdx.x * 256 + threadIdx.x;
  if (id >= 8*496*512) return;
  int k   = id / (496*512);
  int rem = id - k*(496*512);
  int i   = rem >> 9;
  int j   = rem & 511;
  float rt = sqrtf(fabsf(rates[k]));
  float v = 0.0f;
  if (j < 496) v = rt * L[(size_t)k*246016 + i*496 + j];
  u16 h = f2bf(v);
  Wall[stx(k*496 + i, j, 16)] = h;
  Bop2[stx(i, (k << 9) + j, 176)] = h;
}

// K0b: SwC[i, k*512+j] = sqrt(r_k)*L_k[j,i] into Aop2 KB 0..127 (LDS
// transpose). Consumed once by gemmG, then overwritten by Tflat each step.
__global__ __launch_bounds__(256) void k0b(const float* __restrict__ L,
                                           const float* __restrict__ rates,
                                           u16* __restrict__ Aop2){
  __shared__ float tile[32][33];
  int k  = blockIdx.z;
  int i0 = blockIdx.x * 32;
  int j0 = blockIdx.y * 32;
  int tx = threadIdx.x, ty = threadIdx.y;  // 32 x 8
  float rt = sqrtf(fabsf(rates[k]));
  #pragma unroll
  for (int p = 0; p < 4; ++p){
    int j = j0 + ty + p*8;
    int i = i0 + tx;
    float v = 0.0f;
    if (j < 496 && i < 496) v = rt * L[(size_t)k*246016 + j*496 + i];
    tile[ty + p*8][tx] = v;
  }
  __syncthreads();
  #pragma unroll
  for (int p = 0; p < 4; ++p){
    int i = i0 + ty + p*8;
    int j = j0 + tx;
    if (i < 496) Aop2[stx(i, (k << 9) + j, 176)] = f2bf(tile[tx][ty + p*8]);
  }
}

// K0c: rho into Bop2 slot0, zero slot1, d_out = rho0, Wall pads zero.
__global__ __launch_bounds__(256) void k0c(const float* __restrict__ rho0,
                                           u16* __restrict__ Bop2,
                                           u16* __restrict__ Wall,
                                           float* __restrict__ dout){
  int id = blockIdx.x * 256 + threadIdx.x;
  if (id >= 496*512) return;
  int i = id >> 9, j = id & 511;
  float f = (j < 496) ? rho0[(size_t)i*496 + j] : 0.0f;
  Bop2[stx(i, 4608 + j, 176)] = f2bf(f);
  Bop2[stx(i, 5120 + j, 176)] = 0;
  if (j < 496) dout[(size_t)i*496 + j] = f;
  // Wall pad rows 4464..4479 (all cols)
  if (id < 8192) Wall[stx(4464 + (id >> 9), id & 511, 16)] = 0;
  // Wall G-block K-pad cols 496..511 for rows 3968..4463
  else if (id < 8192 + 7936){
    int idx = id - 8192;
    Wall[stx(3968 + (idx >> 4), 496 + (idx & 15), 16)] = 0;
  }
}

// G = SwC * SwC^T (once) -> Wall rows 3968..4463 (staged, KB=16).
__global__ __launch_bounds__(256, 2) void gemmG_k(
    const u16* __restrict__ Asrc, u16* __restrict__ Wall){
  const int t = threadIdx.x, lane = t & 63, w = t >> 6;
  const int wm = w & 1, wn = w >> 1;
  const int tm = blockIdx.x, tn = blockIdx.y;
  const size_t laneu = (size_t)lane * 8;
  const size_t str = (size_t)176 << 9;
  const u16* baseA = Asrc + (((size_t)(tm*4 + wm*2) * 176) << 9) + laneu;
  const u16* baseB = Asrc + (((size_t)(tn*4 + wn*2) * 176) << 9) + laneu;
  f32x4 acc[2][2];
  #pragma unroll
  for (int a = 0; a < 2; ++a)
    #pragma unroll
    for (int b = 0; b < 2; ++b)
      acc[a][b] = (f32x4){0.f, 0.f, 0.f, 0.f};
  kloop<128, 4>(acc, baseA, baseB, str, str);
  const int quad = lane >> 4, c16 = lane & 15;
  #pragma unroll
  for (int mi = 0; mi < 2; ++mi)
  #pragma unroll
  for (int ni = 0; ni < 2; ++ni)
  #pragma unroll
  for (int r = 0; r < 4; ++r){
    int row = tm*64 + wm*32 + mi*16 + quad*4 + r;
    int col = tn*64 + wn*32 + ni*16 + c16;
    if (row < 496 && col < 496)
      Wall[stx(3968 + row, col, 16)] = f2bf(acc[mi][ni][r]);
  }
}

// Phase A: [T_0..T_7, T9] = [L~_0..L~_7, G] * rho. Grid 576, XCD-sliced:
// x=b&7 -> tm = x*9 + (i%9) (each XCD streams its own 1.1 MB Wall slice),
// tn = i/9. DEPTH=8 pipeline. Epilogue: LDS transpose -> 16B coalesced
// stores into Aop2 KB 0..143 (pad cols written 0).
__global__ __launch_bounds__(256, 2) void phaseA_k(
    const u16* __restrict__ Wall, const u16* __restrict__ Bop2,
    int rhoKB, u16* __restrict__ Aop2)
{
  __shared__ float T[64][66];
  int b = blockIdx.x;
  int x = b & 7, i = b >> 3;
  int tm = x*9 + (i % 9);
  int tn = i / 9;
  if (tm >= 70) return;                      // block-uniform
  const int t = threadIdx.x, lane = t & 63, w = t >> 6;
  const int wm = w & 1, wn = w >> 1;
  const size_t laneu = (size_t)lane * 8;
  const size_t strA = (size_t)16 << 9;
  const size_t strB = (size_t)176 << 9;
  const u16* baseA = Wall + (((size_t)(tm*4 + wm*2) * 16) << 9) + laneu;
  const u16* baseB = Bop2 + (((size_t)(tn*4 + wn*2) * 176 + rhoKB) << 9) + laneu;
  f32x4 acc[2][2];
  #pragma unroll
  for (int a = 0; a < 2; ++a)
    #pragma unroll
    for (int c = 0; c < 2; ++c)
      acc[a][c] = (f32x4){0.f, 0.f, 0.f, 0.f};
  kloop<16, 8>(acc, baseA, baseB, strA, strB);

  const int quad = lane >> 4, c16 = lane & 15;
  #pragma unroll
  for (int mi = 0; mi < 2; ++mi)
  #pragma unroll
  for (int ni = 0; ni < 2; ++ni)
  #pragma unroll
  for (int r = 0; r < 4; ++r)
    T[wm*32 + mi*16 + quad*4 + r][wn*32 + ni*16 + c16] = acc[mi][ni][r];
  __syncthreads();
  #pragma unroll
  for (int rep = 0; rep < 2; ++rep){
    int tt = t + rep*256;
    int lr = tt >> 3, oct = tt & 7;
    int row = tm*64 + lr;
    if (row < 4464){
      int colb = tn*64 + oct*8;
      int k = row / 496, i2 = row - k*496;
      union { u16 h[8]; u64 q[2]; } P;
      #pragma unroll
      for (int j = 0; j < 8; ++j)
        P.h[j] = (colb + j < 496) ? f2bf(T[lr][oct*8 + j]) : (u16)0;
      u64* dst = (u64*)&Aop2[stx(i2, (k << 9) + colb, 176)];
      dst[0] = P.q[0]; dst[1] = P.q[1];
    }
  }
}

// Phase-B pair decode with XCD quadrant grouping (R5-proven).
static __device__ __forceinline__ void pairDecode(int b, int& tm, int& tn){
  const int x = b & 7;
  const int o = b >> 3;
  if (x < 6 && o < 16){
    const int qa[6] = {0,0,0,1,1,2};
    const int qb[6] = {1,2,3,2,3,3};
    tm = qa[x]*4 + (o >> 2);
    tn = qb[x]*4 + (o & 3);
  } else {
    int n, grp;
    if (x == 6){ grp = 0; n = o; }
    else if (x == 7){ grp = 1; n = o; }
    else if (x < 3){ grp = 0; n = 17 + x; }
    else { grp = 1; n = 17 + (x - 3); }
    int qbase = (grp == 0) ? ((n < 10) ? 0 : 1) : ((n < 10) ? 2 : 3);
    int m = (n < 10) ? n : n - 10;
    int ii = 0;
    while (m >= 4 - ii){ m -= 4 - ii; ++ii; }
    tm = qbase*4 + ii;
    tn = qbase*4 + ii + m;
  }
}

// Phase B: S = sum_k T_k L~_k^T over K=4096 (8-wave split, 512 kk each,
// DEPTH=8), then rho += DT*(S - 0.5*(T9 + T9^T)) elementwise. 136 blocks =
// lower-tri 32x32 pairs. LDS reduce; finalize: dout + staged bf16 rho
// (+ mirror), 16B coalesced stores. No cross-block communication.
__global__ __launch_bounds__(512, 2) void phaseB_k(
    const u16* __restrict__ Aop2, u16* __restrict__ Bop2,
    float* __restrict__ dout, int rhoKBN)
{
  __shared__ float red[8][32][33];
  const int t = threadIdx.x, lane = t & 63, w = t >> 6;   // w in 0..7
  int tm, tn;
  pairDecode(blockIdx.x, tm, tn);            // tm <= tn
  const size_t laneu = (size_t)lane * 8;
  const size_t str = (size_t)176 << 9;
  const u16* baseA = Aop2 + (((size_t)(tm*2) * 176) << 9) + laneu
                   + ((size_t)(w*16) << 9);
  const u16* baseB = Bop2 + (((size_t)(tn*2) * 176) << 9) + laneu
                   + ((size_t)(w*16) << 9);

  f32x4 acc[2][2];
  #pragma unroll
  for (int a = 0; a < 2; ++a)
    #pragma unroll
    for (int c = 0; c < 2; ++c)
      acc[a][c] = (f32x4){0.f, 0.f, 0.f, 0.f};
  kloop<16, 8>(acc, baseA, baseB, str, str);

  const int quad = lane >> 4, c16 = lane & 15;
  #pragma unroll
  for (int mi = 0; mi < 2; ++mi)
  #pragma unroll
  for (int ni = 0; ni < 2; ++ni)
  #pragma unroll
  for (int r = 0; r < 4; ++r)
    red[w][mi*16 + quad*4 + r][ni*16 + c16] = acc[mi][ni][r];
  __syncthreads();

  // pass 1: 8-wave reduce + T9 anticommutator + rho update; rnew -> red[0]
  #pragma unroll
  for (int c = t; c < 1024; c += 512){
    int lr = c >> 5, lc = c & 31;
    float sum = 0.0f;
    #pragma unroll
    for (int ww = 0; ww < 8; ++ww) sum += red[ww][lr][lc];
    int row = tm*32 + lr, col = tn*32 + lc;
    float rnew = 0.0f;
    if (row < 496 && col < 496){
      float t9a = bf2f(Aop2[stx(row, 4096 + col, 176)]);
      float t9b = bf2f(Aop2[stx(col, 4096 + row, 176)]);
      int e = row*496 + col;
      rnew = dout[e] + DT_STEP * (sum - 0.5f*(t9a + t9b));
      dout[e] = rnew;
      if (tm != tn) dout[col*496 + row] = rnew;
    }
    red[0][lr][lc] = rnew;
  }
  __syncthreads();

  // pass 2: staged bf16 rho, 16B coalesced stores (threads 0..255)
  if (t < 256){
    int tt = t & 127;
    int lr = tt >> 2, oct = tt & 3;
    if (t < 128){
      int row = tm*32 + lr, colb = tn*32 + oct*8;
      if (row < 496 && colb < 496){
        union { u16 h[8]; u64 q[2]; } B_;
        #pragma unroll
        for (int j = 0; j < 8; ++j) B_.h[j] = f2bf(red[0][lr][oct*8 + j]);
        u64* dst = (u64*)&Bop2[stx(row, (rhoKBN << 5) + colb, 176)];
        dst[0] = B_.q[0]; dst[1] = B_.q[1];
      }
    } else if (tm != tn){
      int row = tn*32 + lr, colb = tm*32 + oct*8;   // mirror tile
      if (row < 496){
        union { u16 h[8]; u64 q[2]; } B_;
        #pragma unroll
        for (int j = 0; j < 8; ++j) B_.h[j] = f2bf(red[0][oct*8 + j][lr]);
        u64* dst = (u64*)&Bop2[stx(row, (rhoKBN << 5) + colb, 176)];
        dst[0] = B_.q[0]; dst[1] = B_.q[1];
      }
    }
  }
}

extern "C" void kernel_launch(void* const* d_in, const int* in_sizes, int n_in,
                              void* d_out, int out_size, void* d_ws, size_t ws_size,
                              hipStream_t stream)
{
  (void)in_sizes; (void)n_in; (void)out_size;
  if (ws_size < WS_NEED) return;
  const float* rho0  = (const float*)d_in[0];
  // d_in[1] (H_real) provably does not affect the real forward output.
  const float* L     = (const float*)d_in[2];
  const float* rates = (const float*)d_in[3];
  float* dout = (float*)d_out;
  char* ws = (char*)d_ws;
  u16* Wall = (u16*)(ws + OFF_WALL);
  u16* Aop2 = (u16*)(ws + OFF_AOP2);
  u16* Bop2 = (u16*)(ws + OFF_BOP2);

  k0a<<<dim3((8*496*512 + 255)/256), dim3(256), 0, stream>>>(L, rates, Wall, Bop2);
  k0b<<<dim3(16,16,8), dim3(32,8), 0, stream>>>(L, rates, Aop2);
  k0c<<<dim3((496*512 + 255)/256), dim3(256), 0, stream>>>(rho0, Bop2, Wall, dout);
  // G = sum_k r_k L_k^T L_k -> Wall rows 3968.. (consumes SwC in Aop2)
  gemmG_k<<<dim3(8,8), dim3(256), 0, stream>>>(Aop2, Wall);

  for (int s = 0; s < 32; ++s){
    int rhoKB  = 144 + 16*(s & 1);
    int rhoKBN = 144 + 16*((s+1) & 1);
    // phase A: T_k = L~_k rho (k=0..7) and T9 = G rho
    phaseA_k<<<dim3(576), dim3(256), 0, stream>>>(Wall, Bop2, rhoKB, Aop2);
    // phase B: rho += DT*( sum_k T_k L~_k^T - 0.5(T9 + T9^T) ), symmetric
    phaseB_k<<<dim3(136), dim3(512), 0, stream>>>(Aop2, Bop2, dout, rhoKBN);
  }
}